// Round 4
// baseline (214.588 us; speedup 1.0000x reference)
//
#include <hip/hip_runtime.h>
#include <math.h>

#ifndef M_PI
#define M_PI 3.14159265358979323846
#endif

// SPH solver step — pull formulation, zero global atomics.
// Build: two-level LDS bucket sort by receiver (coarse bin i>>8, fine slot
// i&255), pairs packed as (slot<<jbits)|j in a single int.
// Reference facts exploited:
//   * v_i - u_i == 0  -> transport stress term Ar == 0 exactly
//   * p_bg_i == 0     -> dvdt == 0 exactly (cols 5..7 written as zeros in k_rho)
//   * eta_i == eta_j  -> eta_ij compile-time constant
//   * p = 100*(rho-1) -> particle record {r,rho | v,p} is 32B = 1 cache line
static constexpr float kSigma = (float)(3.0 / 359.0 / M_PI);  // H = 1
static constexpr float kPRef  = 100.0f;
static constexpr float kEps   = 1e-8f;
static constexpr float kEta   = (float)(2.0 * 0.01 * 0.01 / (0.01 + 0.01 + 1e-8));

#define CHUNKA 2048   // edges per block in hist/split (more blocks = more waves)

__device__ __forceinline__ float pow5f(float t) { float t2 = t * t; return t2 * t2 * t; }
__device__ __forceinline__ float pow4f(float t) { float t2 = t * t; return t2 * t2; }

// ---------------- pack positions; also plant offset[n] = E ----------------
__global__ void k_pack(const float* __restrict__ r, float4* __restrict__ pos4,
                       int* __restrict__ offset, int n, int E) {
    int i = blockIdx.x * blockDim.x + threadIdx.x;
    if (i == 0) offset[n] = E;
    if (i >= n) return;
    pos4[i] = make_float4(r[3 * i], r[3 * i + 1], r[3 * i + 2], 0.f);
}

// ---------------- coarse histogram: LDS atomics only ----------------
__global__ void k_hist(const int* __restrict__ i_s, int* __restrict__ ghist,
                       int nbA, int nbins, int E, int shift) {
    __shared__ int h[512];
    int t = threadIdx.x, blk = blockIdx.x;
    for (int b = t; b < nbins; b += 256) h[b] = 0;
    __syncthreads();
    int base = blk * CHUNKA;
    int end = min(base + CHUNKA, E);
    for (int k = base + t; k < end; k += 256)
        atomicAdd(&h[i_s[k] >> shift], 1);
    __syncthreads();
    for (int b = t; b < nbins; b += 256)
        ghist[b * nbA + blk] = h[b];   // bin-major for the scan
}

// ---------------- 2-kernel scan (scan_add folded into consumers) ----------
__global__ void k_scan_block(const int* __restrict__ in, int* __restrict__ out,
                             int* __restrict__ bsum, int m) {
    __shared__ int s[256];
    int t = threadIdx.x;
    int i = blockIdx.x * 256 + t;
    int x = (i < m) ? in[i] : 0;
    s[t] = x;
    __syncthreads();
    for (int d = 1; d < 256; d <<= 1) {
        int v = (t >= d) ? s[t - d] : 0;
        __syncthreads();
        s[t] += v;
        __syncthreads();
    }
    if (i < m) out[i] = s[t] - x;            // block-local exclusive
    if (t == 255) bsum[blockIdx.x] = s[255];
}

// single-block loop scan of block sums (handles any nb)
__global__ void k_scan_bsums(const int* __restrict__ bsum, int* __restrict__ bscan, int nb) {
    __shared__ int s[512];
    __shared__ int carry;
    int t = threadIdx.x;
    if (t == 0) carry = 0;
    __syncthreads();
    for (int base = 0; base < nb; base += 512) {
        int i = base + t;
        int x = (i < nb) ? bsum[i] : 0;
        s[t] = x;
        __syncthreads();
        for (int d = 1; d < 512; d <<= 1) {
            int v = (t >= d) ? s[t - d] : 0;
            __syncthreads();
            s[t] += v;
            __syncthreads();
        }
        if (i < nb) bscan[i] = s[t] - x + carry;
        __syncthreads();
        if (t == 511) carry += s[511];
        __syncthreads();
    }
}

// ---------------- coarse split: packed (slot,j) into coarse bins ----------
__global__ void k_split(const int* __restrict__ i_s, const int* __restrict__ j_s,
                        const int* __restrict__ gscan, const int* __restrict__ bscan,
                        int* __restrict__ pairs, int nbA, int nbins, int E,
                        int shift, int jbits) {
    __shared__ int cur[512];
    int t = threadIdx.x, blk = blockIdx.x;
    for (int b = t; b < nbins; b += 256) {
        int idx = b * nbA + blk;
        cur[b] = gscan[idx] + bscan[idx >> 8];
    }
    __syncthreads();
    int fmask = (1 << shift) - 1;
    int base = blk * CHUNKA;
    int end = min(base + CHUNKA, E);
    for (int k = base + t; k < end; k += 256) {
        int i = i_s[k];
        int pos = atomicAdd(&cur[i >> shift], 1);          // LDS atomic
        pairs[pos] = ((i & fmask) << jbits) | j_s[k];
    }
}

// ---------------- fine sort within each coarse bin (512 thr / 256 slots) ---
__global__ void k_binsort(const int* __restrict__ pairs, const int* __restrict__ gscan,
                          const int* __restrict__ bscan, int* __restrict__ sortedJ,
                          int* __restrict__ offset, int nbA, int n, int E,
                          int shift, int jbits, int m) {
    __shared__ int h[512];
    __shared__ int sse[2];
    int b = blockIdx.x, t = threadIdx.x;
    int fine = 1 << shift;
    if (t < fine) h[t] = 0;
    if (t == 0) {
        int i0 = b * nbA;
        sse[0] = gscan[i0] + bscan[i0 >> 8];
        int i1 = (b + 1) * nbA;
        sse[1] = (i1 < m) ? (gscan[i1] + bscan[i1 >> 8]) : E;
    }
    __syncthreads();
    int s = sse[0], e = sse[1];
    int jm = (1 << jbits) - 1;
    for (int k = s + t; k < e; k += 512)
        atomicAdd(&h[pairs[k] >> jbits], 1);               // LDS atomic
    __syncthreads();
    int x = (t < fine) ? h[t] : 0;
    for (int d = 1; d < fine; d <<= 1) {                   // inclusive scan
        int v = (t >= d && t < fine) ? h[t - d] : 0;
        __syncthreads();
        if (t < fine) h[t] += v;
        __syncthreads();
    }
    if (t < fine) {
        int i = (b << shift) + t;
        if (i < n) offset[i] = s + h[t] - x;               // CSR starts, coalesced
    }
    __syncthreads();
    if (t < fine) h[t] = s + h[t] - x;                     // fine cursors
    __syncthreads();
    for (int k = s + t; k < e; k += 512) {
        int pr = pairs[k];
        int pos = atomicAdd(&h[pr >> jbits], 1);           // LDS atomic
        sortedJ[pos] = pr & jm;                            // L2-hot bin window
    }
}

// ---------------- pass 1: density (fused per-particle state) ----------------
// Half-wave (32 lanes) per particle; lane 0 writes out cols 0,1,5,6,7 and the
// 32B particle record {r.xyz, rho | v.xyz, p} used by k_acc.
__global__ void k_rho(const float4* __restrict__ pos4, const float* __restrict__ v,
                      const int* __restrict__ sortedJ, const int* __restrict__ offset,
                      float4* __restrict__ pv8, float* __restrict__ out, int n) {
    int p = (int)((blockIdx.x * (size_t)blockDim.x + threadIdx.x) >> 5);
    int lane = threadIdx.x & 31;
    if (p >= n) return;
    float4 ri = pos4[p];                // broadcast
    int s = offset[p], e = offset[p + 1];
    float acc = 0.f;
    for (int k = s + lane; k < e; k += 32) {
        int j = sortedJ[k];
        float4 rj = pos4[j];            // divergent gather (1.6MB, L2-hot)
        float dx = ri.x - rj.x, dy = ri.y - rj.y, dz = ri.z - rj.z;
        float d = sqrtf(dx * dx + dy * dy + dz * dz);
        float t1 = fmaxf(1.f - d, 0.f);
        float t2 = fmaxf(2.f - d, 0.f);
        float t3 = fmaxf(3.f - d, 0.f);
        acc += kSigma * (pow5f(t3) - 6.f * pow5f(t2) + 15.f * pow5f(t1));
    }
    for (int o = 16; o; o >>= 1) acc += __shfl_down(acc, o, 32);
    if (lane == 0) {
        float rh = acc;
        float pp = kPRef * (rh - 1.0f);
        pv8[2 * p]     = make_float4(ri.x, ri.y, ri.z, rh);
        pv8[2 * p + 1] = make_float4(v[3 * p], v[3 * p + 1], v[3 * p + 2], pp);
        float* o = out + (size_t)p * 8;
        o[0] = rh;
        o[1] = pp;
        o[5] = 0.f; o[6] = 0.f; o[7] = 0.f;   // dvdt == 0 exactly
    }
}

// ---------------- pass 2: acceleration ----------------
__global__ void k_acc(const float4* __restrict__ pv8, const int* __restrict__ sortedJ,
                      const int* __restrict__ offset, float* __restrict__ out, int n) {
    int p = (int)((blockIdx.x * (size_t)blockDim.x + threadIdx.x) >> 5);
    int lane = threadIdx.x & 31;
    if (p >= n) return;
    float4 ai = pv8[2 * p], bi = pv8[2 * p + 1];   // broadcast {r,rho | v,p}
    float rho_i = ai.w, p_i = bi.w;
    float inv_i = 1.0f / rho_i;
    float inv2_i = inv_i * inv_i;
    int s = offset[p], e = offset[p + 1];
    float ax = 0.f, ay = 0.f, az = 0.f;
    for (int k = s + lane; k < e; k += 32) {
        int j = sortedJ[k];
        float4 aj = pv8[2 * j];                    // same 64B line
        float4 bj = pv8[2 * j + 1];
        float rho_j = aj.w, p_j = bj.w;
        float dx = ai.x - aj.x, dy = ai.y - aj.y, dz = ai.z - aj.z;
        float d = sqrtf(dx * dx + dy * dy + dz * dz);
        float t1 = fmaxf(1.f - d, 0.f);
        float t2 = fmaxf(2.f - d, 0.f);
        float t3 = fmaxf(3.f - d, 0.f);
        float gw = kSigma * (-5.f * pow4f(t3) + 30.f * pow4f(t2) - 75.f * pow4f(t1));
        float inv_j = 1.0f / rho_j;
        float c = (inv2_i + inv_j * inv_j) * gw / (d + kEps);
        float p_ij = (rho_j * p_i + rho_i * p_j) / (rho_i + rho_j);
        ax += c * (kEta * (bi.x - bj.x) - p_ij * dx);
        ay += c * (kEta * (bi.y - bj.y) - p_ij * dy);
        az += c * (kEta * (bi.z - bj.z) - p_ij * dz);
    }
    for (int o = 16; o; o >>= 1) {
        ax += __shfl_down(ax, o, 32);
        ay += __shfl_down(ay, o, 32);
        az += __shfl_down(az, o, 32);
    }
    if (lane == 0) {
        float* o = out + (size_t)p * 8 + 2;
        o[0] = ax; o[1] = ay; o[2] = az;
    }
}

// ---------------- launch ----------------
static inline char* wcarve(char*& ws, size_t bytes) {
    char* p = ws;
    ws += (bytes + 255) & ~(size_t)255;
    return p;
}

extern "C" void kernel_launch(void* const* d_in, const int* in_sizes, int n_in,
                              void* d_out, int out_size, void* d_ws, size_t ws_size,
                              hipStream_t stream) {
    const float* r = (const float*)d_in[0];
    const float* v = (const float*)d_in[1];
    const int* i_s = (const int*)d_in[2];
    const int* j_s = (const int*)d_in[3];
    int n = in_sizes[0] / 3;
    int E = in_sizes[2];
    float* out = (float*)d_out;

    int shift = 8;                                 // fine slots = 256
    int nbins = ((n - 1) >> shift) + 1;
    while (nbins > 512) { shift++; nbins = ((n - 1) >> shift) + 1; }  // safety
    int jbits = 1;
    while ((1 << jbits) < n) jbits++;              // 17 for n = 100k

    int nbA = (E + CHUNKA - 1) / CHUNKA;           // 1563 for E = 3.2M
    int m = nbins * nbA;                           // histogram length (~611k)
    int nb2 = (m + 255) / 256;

    char* ws = (char*)d_ws;
    float4* pos4   = (float4*)wcarve(ws, (size_t)n * 16);
    float4* pv8    = (float4*)wcarve(ws, (size_t)n * 32);
    int*    offset = (int*)wcarve(ws, (size_t)(n + 1) * 4);
    int*    ghist  = (int*)wcarve(ws, (size_t)m * 4);
    int*    gscan  = (int*)wcarve(ws, (size_t)m * 4);
    int*    bsum   = (int*)wcarve(ws, (size_t)nb2 * 4);
    int*    bscan  = (int*)wcarve(ws, (size_t)nb2 * 4);
    int*    pairs  = (int*)wcarve(ws, (size_t)E * 4);
    int*    sortedJ= (int*)wcarve(ws, (size_t)E * 4);

    const int bs = 256;
    int gn = (n + bs - 1) / bs;
    int gp = (n + 7) / 8;                          // 8 half-waves per block

    k_pack<<<gn, bs, 0, stream>>>(r, pos4, offset, n, E);
    k_hist<<<nbA, 256, 0, stream>>>(i_s, ghist, nbA, nbins, E, shift);
    k_scan_block<<<nb2, 256, 0, stream>>>(ghist, gscan, bsum, m);
    k_scan_bsums<<<1, 512, 0, stream>>>(bsum, bscan, nb2);
    k_split<<<nbA, 256, 0, stream>>>(i_s, j_s, gscan, bscan, pairs, nbA, nbins, E, shift, jbits);
    k_binsort<<<nbins, 512, 0, stream>>>(pairs, gscan, bscan, sortedJ, offset, nbA, n, E, shift, jbits, m);
    k_rho<<<gp, bs, 0, stream>>>(pos4, v, sortedJ, offset, pv8, out, n);
    k_acc<<<gp, bs, 0, stream>>>(pv8, sortedJ, offset, out, n);
}

// Round 5
// 214.453 us; speedup vs baseline: 1.0006x; 1.0006x over previous
//
#include <hip/hip_runtime.h>
#include <math.h>

#ifndef M_PI
#define M_PI 3.14159265358979323846
#endif

// SPH solver step — pull formulation, zero global atomics, no fine sort.
// Build: coarse bucket split by receiver bin (i>>8, 256 particles/bin) with
// long scatter runs (CHUNKA=8192 keeps per-(block,bin) runs > a cache line).
// Compute: one block per coarse bin; bin's own particles staged in LDS, fine
// reduction via LDS float atomics indexed by i&255; j-side gathered from
// L2-hot tables. No binsort, no CSR, no sortedJ.
// Reference facts exploited:
//   * v_i - u_i == 0  -> transport stress term Ar == 0 exactly
//   * p_bg_i == 0     -> dvdt == 0 exactly (cols 5..7 written as zeros)
//   * eta_i == eta_j  -> eta_ij compile-time constant
//   * p = 100*(rho-1) -> j-side record {r,rho | v,p} is 32B = 1 cache line
static constexpr float kSigma = (float)(3.0 / 359.0 / M_PI);  // H = 1
static constexpr float kPRef  = 100.0f;
static constexpr float kEps   = 1e-8f;
static constexpr float kEta   = (float)(2.0 * 0.01 * 0.01 / (0.01 + 0.01 + 1e-8));

#define CHUNKA 8192   // edges per hist/split block: runs of ~8192/nbins ints

__device__ __forceinline__ float pow5f(float t) { float t2 = t * t; return t2 * t2 * t; }
__device__ __forceinline__ float pow4f(float t) { float t2 = t * t; return t2 * t2; }

// ---------------- pack positions into 16B records ----------------
__global__ void k_pack(const float* __restrict__ r, float4* __restrict__ pos4, int n) {
    int i = blockIdx.x * blockDim.x + threadIdx.x;
    if (i >= n) return;
    pos4[i] = make_float4(r[3 * i], r[3 * i + 1], r[3 * i + 2], 0.f);
}

// ---------------- coarse histogram: LDS atomics only ----------------
__global__ void k_hist(const int* __restrict__ i_s, int* __restrict__ ghist,
                       int nbA, int nbins, int E, int shift) {
    __shared__ int h[512];
    int t = threadIdx.x, blk = blockIdx.x;
    for (int b = t; b < nbins; b += 512) h[b] = 0;
    __syncthreads();
    int base = blk * CHUNKA;
    int end = min(base + CHUNKA, E);
    for (int k = base + t; k < end; k += 512)
        atomicAdd(&h[i_s[k] >> shift], 1);
    __syncthreads();
    for (int b = t; b < nbins; b += 512)
        ghist[b * nbA + blk] = h[b];   // bin-major for the scan
}

// ---------------- 2-kernel scan (final add folded into consumers) ----------
__global__ void k_scan_block(const int* __restrict__ in, int* __restrict__ out,
                             int* __restrict__ bsum, int m) {
    __shared__ int s[256];
    int t = threadIdx.x;
    int i = blockIdx.x * 256 + t;
    int x = (i < m) ? in[i] : 0;
    s[t] = x;
    __syncthreads();
    for (int d = 1; d < 256; d <<= 1) {
        int v = (t >= d) ? s[t - d] : 0;
        __syncthreads();
        s[t] += v;
        __syncthreads();
    }
    if (i < m) out[i] = s[t] - x;            // block-local exclusive
    if (t == 255) bsum[blockIdx.x] = s[255];
}

// single-block loop scan of block sums (handles any nb)
__global__ void k_scan_bsums(const int* __restrict__ bsum, int* __restrict__ bscan, int nb) {
    __shared__ int s[512];
    __shared__ int carry;
    int t = threadIdx.x;
    if (t == 0) carry = 0;
    __syncthreads();
    for (int base = 0; base < nb; base += 512) {
        int i = base + t;
        int x = (i < nb) ? bsum[i] : 0;
        s[t] = x;
        __syncthreads();
        for (int d = 1; d < 512; d <<= 1) {
            int v = (t >= d) ? s[t - d] : 0;
            __syncthreads();
            s[t] += v;
            __syncthreads();
        }
        if (i < nb) bscan[i] = s[t] - x + carry;
        __syncthreads();
        if (t == 511) carry += s[511];
        __syncthreads();
    }
}

// ---------------- coarse split: packed (slot,j) into coarse bins ----------
__global__ void k_split(const int* __restrict__ i_s, const int* __restrict__ j_s,
                        const int* __restrict__ gscan, const int* __restrict__ bscan,
                        int* __restrict__ pairs, int nbA, int nbins, int E,
                        int shift, int jbits) {
    __shared__ int cur[512];
    int t = threadIdx.x, blk = blockIdx.x;
    for (int b = t; b < nbins; b += 512) {
        int idx = b * nbA + blk;
        cur[b] = gscan[idx] + bscan[idx >> 8];
    }
    __syncthreads();
    int fmask = (1 << shift) - 1;
    int base = blk * CHUNKA;
    int end = min(base + CHUNKA, E);
    for (int k = base + t; k < end; k += 512) {
        int i = i_s[k];
        int pos = atomicAdd(&cur[i >> shift], 1);          // LDS atomic
        pairs[pos] = ((i & fmask) << jbits) | j_s[k];
    }
}

// ---------------- pass 1: density — one block per coarse bin ----------------
// Reads the bin's pairs run coalesced; i-side from LDS; j-side gathered from
// the L2-hot pos4 table; reduction via LDS float atomics by fine slot.
// Epilogue (fused k_state): writes out cols 0,1,5,6,7 and 32B records
// {r,rho | v,p} into pv8, all coalesced.
__global__ void k_rho_bin(const float4* __restrict__ pos4, const float* __restrict__ v,
                          const int* __restrict__ pairs, const int* __restrict__ gscan,
                          const int* __restrict__ bscan, float4* __restrict__ pv8,
                          float* __restrict__ out, int nbA, int n, int E,
                          int shift, int jbits, int m) {
    __shared__ float srho[512];
    __shared__ float4 spos[512];
    __shared__ int sse[2];
    int b = blockIdx.x, t = threadIdx.x;
    int slots = 1 << shift;
    int lo = b << shift;
    for (int s0 = t; s0 < slots; s0 += 1024) {
        srho[s0] = 0.f;
        int i = lo + s0;
        spos[s0] = (i < n) ? pos4[i] : make_float4(0.f, 0.f, 0.f, 0.f);
    }
    if (t == 0) {
        int i0 = b * nbA;
        sse[0] = gscan[i0] + bscan[i0 >> 8];
        int i1 = (b + 1) * nbA;
        sse[1] = (i1 < m) ? (gscan[i1] + bscan[i1 >> 8]) : E;
    }
    __syncthreads();
    int s = sse[0], e = sse[1];
    int jm = (1 << jbits) - 1;
    for (int k = s + t; k < e; k += 1024) {
        int pr = pairs[k];                   // coalesced
        int slot = pr >> jbits, j = pr & jm;
        float4 rj = pos4[j];                 // divergent gather (1.6MB, L2-hot)
        float4 ri = spos[slot];
        float dx = ri.x - rj.x, dy = ri.y - rj.y, dz = ri.z - rj.z;
        float d = sqrtf(dx * dx + dy * dy + dz * dz);
        float t1 = fmaxf(1.f - d, 0.f);
        float t2 = fmaxf(2.f - d, 0.f);
        float t3 = fmaxf(3.f - d, 0.f);
        float w = kSigma * (pow5f(t3) - 6.f * pow5f(t2) + 15.f * pow5f(t1));
        atomicAdd(&srho[slot], w);           // LDS float atomic
    }
    __syncthreads();
    for (int s0 = t; s0 < slots; s0 += 1024) {
        int i = lo + s0;
        if (i >= n) continue;
        float rh = srho[s0];
        float pp = kPRef * (rh - 1.0f);
        float4 sp = spos[s0];
        pv8[2 * i]     = make_float4(sp.x, sp.y, sp.z, rh);
        pv8[2 * i + 1] = make_float4(v[3 * i], v[3 * i + 1], v[3 * i + 2], pp);
        float* o = out + (size_t)i * 8;
        o[0] = rh;
        o[1] = pp;
        o[5] = 0.f; o[6] = 0.f; o[7] = 0.f;  // dvdt == 0 exactly
    }
}

// ---------------- pass 2: acceleration — one block per coarse bin ----------
__global__ void k_acc_bin(const float4* __restrict__ pv8, const int* __restrict__ pairs,
                          const int* __restrict__ gscan, const int* __restrict__ bscan,
                          float* __restrict__ out, int nbA, int n, int E,
                          int shift, int jbits, int m) {
    __shared__ float sax[512], say[512], saz[512];
    __shared__ float4 sab[1024];             // {r,rho | v,p} interleaved per slot
    __shared__ int sse[2];
    int b = blockIdx.x, t = threadIdx.x;
    int slots = 1 << shift;
    int lo = b << shift;
    for (int s0 = t; s0 < slots; s0 += 1024) { sax[s0] = 0.f; say[s0] = 0.f; saz[s0] = 0.f; }
    for (int q = t; q < 2 * slots; q += 1024) {
        int gi = 2 * lo + q;
        sab[q] = (gi < 2 * n) ? pv8[gi] : make_float4(0.f, 0.f, 0.f, 0.f);
    }
    if (t == 0) {
        int i0 = b * nbA;
        sse[0] = gscan[i0] + bscan[i0 >> 8];
        int i1 = (b + 1) * nbA;
        sse[1] = (i1 < m) ? (gscan[i1] + bscan[i1 >> 8]) : E;
    }
    __syncthreads();
    int s = sse[0], e = sse[1];
    int jm = (1 << jbits) - 1;
    for (int k = s + t; k < e; k += 1024) {
        int pr = pairs[k];                   // coalesced
        int slot = pr >> jbits, j = pr & jm;
        float4 aj = pv8[2 * j];              // divergent gather, 64B line
        float4 bj = pv8[2 * j + 1];          // same line (L1 hit)
        float4 ai = sab[2 * slot];
        float4 bi = sab[2 * slot + 1];
        float rho_i = ai.w, p_i = bi.w;
        float rho_j = aj.w, p_j = bj.w;
        float dx = ai.x - aj.x, dy = ai.y - aj.y, dz = ai.z - aj.z;
        float d = sqrtf(dx * dx + dy * dy + dz * dz);
        float t1 = fmaxf(1.f - d, 0.f);
        float t2 = fmaxf(2.f - d, 0.f);
        float t3 = fmaxf(3.f - d, 0.f);
        float gw = kSigma * (-5.f * pow4f(t3) + 30.f * pow4f(t2) - 75.f * pow4f(t1));
        float inv_i = 1.0f / rho_i, inv_j = 1.0f / rho_j;
        float c = (inv_i * inv_i + inv_j * inv_j) * gw / (d + kEps);
        float p_ij = (rho_j * p_i + rho_i * p_j) / (rho_i + rho_j);
        atomicAdd(&sax[slot], c * (kEta * (bi.x - bj.x) - p_ij * dx));
        atomicAdd(&say[slot], c * (kEta * (bi.y - bj.y) - p_ij * dy));
        atomicAdd(&saz[slot], c * (kEta * (bi.z - bj.z) - p_ij * dz));
    }
    __syncthreads();
    for (int s0 = t; s0 < slots; s0 += 1024) {
        int i = lo + s0;
        if (i >= n) continue;
        float* o = out + (size_t)i * 8 + 2;
        o[0] = sax[s0]; o[1] = say[s0]; o[2] = saz[s0];
    }
}

// ---------------- launch ----------------
static inline char* wcarve(char*& ws, size_t bytes) {
    char* p = ws;
    ws += (bytes + 255) & ~(size_t)255;
    return p;
}

extern "C" void kernel_launch(void* const* d_in, const int* in_sizes, int n_in,
                              void* d_out, int out_size, void* d_ws, size_t ws_size,
                              hipStream_t stream) {
    const float* r = (const float*)d_in[0];
    const float* v = (const float*)d_in[1];
    const int* i_s = (const int*)d_in[2];
    const int* j_s = (const int*)d_in[3];
    int n = in_sizes[0] / 3;
    int E = in_sizes[2];
    float* out = (float*)d_out;

    int shift = 8;                                 // 256 particles per coarse bin
    int nbins = ((n - 1) >> shift) + 1;
    while (nbins > 512) { shift++; nbins = ((n - 1) >> shift) + 1; }  // safety
    int jbits = 1;
    while ((1 << jbits) < n) jbits++;              // 17 for n = 100k

    int nbA = (E + CHUNKA - 1) / CHUNKA;           // 391 for E = 3.2M
    int m = nbins * nbA;                           // histogram length
    int nb2 = (m + 255) / 256;

    char* ws = (char*)d_ws;
    float4* pos4  = (float4*)wcarve(ws, (size_t)n * 16);
    float4* pv8   = (float4*)wcarve(ws, (size_t)n * 32);
    int*    ghist = (int*)wcarve(ws, (size_t)m * 4);
    int*    gscan = (int*)wcarve(ws, (size_t)m * 4);
    int*    bsum  = (int*)wcarve(ws, (size_t)nb2 * 4);
    int*    bscan = (int*)wcarve(ws, (size_t)nb2 * 4);
    int*    pairs = (int*)wcarve(ws, (size_t)E * 4);

    const int bs = 256;
    int gn = (n + bs - 1) / bs;

    k_pack<<<gn, bs, 0, stream>>>(r, pos4, n);
    k_hist<<<nbA, 512, 0, stream>>>(i_s, ghist, nbA, nbins, E, shift);
    k_scan_block<<<nb2, 256, 0, stream>>>(ghist, gscan, bsum, m);
    k_scan_bsums<<<1, 512, 0, stream>>>(bsum, bscan, nb2);
    k_split<<<nbA, 512, 0, stream>>>(i_s, j_s, gscan, bscan, pairs, nbA, nbins, E, shift, jbits);
    k_rho_bin<<<nbins, 1024, 0, stream>>>(pos4, v, pairs, gscan, bscan, pv8, out, nbA, n, E, shift, jbits, m);
    k_acc_bin<<<nbins, 1024, 0, stream>>>(pv8, pairs, gscan, bscan, out, nbA, n, E, shift, jbits, m);
}

// Round 6
// 210.938 us; speedup vs baseline: 1.0173x; 1.0167x over previous
//
#include <hip/hip_runtime.h>
#include <math.h>

#ifndef M_PI
#define M_PI 3.14159265358979323846
#endif

// SPH solver step — pull formulation, zero global atomics.
// Build: coarse bucket split by receiver bin (i>>8, 256 particles/bin).
//   - hist at fine granularity (CHUNKH=4096, 782 blocks) for parallelism
//   - split at coarse granularity (CHUNKS=8192, 391 blocks) for long write
//     runs (>= cache line; round-4 lesson: short runs inflate writes 4-6x)
//   - pairs within a bin are ordered by hist-chunk, so split block b starts
//     its cursor at the scanned offset of hist-chunk 2b. 
// Compute: 8 sub-blocks per bin (3128 blocks x 256 thr, ~12/CU — round-5
// lesson: 391x1024 gave 1.5 blocks/CU load imbalance). LDS accumulators per
// sub-block, per-sub global partials (coalesced), tiny 8-way reduce kernels.
// Reference facts exploited:
//   * v_i - u_i == 0  -> transport stress term Ar == 0 exactly
//   * p_bg_i == 0     -> dvdt == 0 exactly (cols 5..7 written as zeros)
//   * eta_i == eta_j  -> eta_ij compile-time constant
//   * p = 100*(rho-1) -> j-side record {r,rho | v,p} is 32B = 1 cache line
static constexpr float kSigma = (float)(3.0 / 359.0 / M_PI);  // H = 1
static constexpr float kPRef  = 100.0f;
static constexpr float kEps   = 1e-8f;
static constexpr float kEta   = (float)(2.0 * 0.01 * 0.01 / (0.01 + 0.01 + 1e-8));

#define CHUNKH 4096   // hist granularity
#define CHUNKS 8192   // split granularity (2 hist chunks)
#define NSUB   8      // compute sub-blocks per coarse bin

__device__ __forceinline__ float pow5f(float t) { float t2 = t * t; return t2 * t2 * t; }
__device__ __forceinline__ float pow4f(float t) { float t2 = t * t; return t2 * t2; }

// ---------------- pack positions into 16B records ----------------
__global__ void k_pack(const float* __restrict__ r, float4* __restrict__ pos4, int n) {
    int i = blockIdx.x * blockDim.x + threadIdx.x;
    if (i >= n) return;
    pos4[i] = make_float4(r[3 * i], r[3 * i + 1], r[3 * i + 2], 0.f);
}

// ---------------- coarse histogram: LDS atomics only ----------------
__global__ void k_hist(const int* __restrict__ i_s, int* __restrict__ ghist,
                       int nbAh, int nbins, int E, int shift) {
    __shared__ int h[512];
    int t = threadIdx.x, blk = blockIdx.x;
    for (int b = t; b < nbins; b += 256) h[b] = 0;
    __syncthreads();
    int base = blk * CHUNKH;
    int end = min(base + CHUNKH, E);
    for (int k = base + t; k < end; k += 256)
        atomicAdd(&h[i_s[k] >> shift], 1);
    __syncthreads();
    for (int b = t; b < nbins; b += 256)
        ghist[b * nbAh + blk] = h[b];   // bin-major for the scan
}

// ---------------- 2-kernel scan (final add folded into consumers) ----------
__global__ void k_scan_block(const int* __restrict__ in, int* __restrict__ out,
                             int* __restrict__ bsum, int m) {
    __shared__ int s[256];
    int t = threadIdx.x;
    int i = blockIdx.x * 256 + t;
    int x = (i < m) ? in[i] : 0;
    s[t] = x;
    __syncthreads();
    for (int d = 1; d < 256; d <<= 1) {
        int v = (t >= d) ? s[t - d] : 0;
        __syncthreads();
        s[t] += v;
        __syncthreads();
    }
    if (i < m) out[i] = s[t] - x;            // block-local exclusive
    if (t == 255) bsum[blockIdx.x] = s[255];
}

// single-block loop scan of block sums (handles any nb)
__global__ void k_scan_bsums(const int* __restrict__ bsum, int* __restrict__ bscan, int nb) {
    __shared__ int s[512];
    __shared__ int carry;
    int t = threadIdx.x;
    if (t == 0) carry = 0;
    __syncthreads();
    for (int base = 0; base < nb; base += 512) {
        int i = base + t;
        int x = (i < nb) ? bsum[i] : 0;
        s[t] = x;
        __syncthreads();
        for (int d = 1; d < 512; d <<= 1) {
            int v = (t >= d) ? s[t - d] : 0;
            __syncthreads();
            s[t] += v;
            __syncthreads();
        }
        if (i < nb) bscan[i] = s[t] - x + carry;
        __syncthreads();
        if (t == 511) carry += s[511];
        __syncthreads();
    }
}

__device__ __forceinline__ int scanned(const int* __restrict__ gscan,
                                       const int* __restrict__ bscan, int idx) {
    return gscan[idx] + bscan[idx >> 8];
}

// ---------------- coarse split: packed (slot,j) into coarse bins ----------
// Block b covers hist chunks 2b, 2b+1; cursors start at chunk 2b's offsets.
__global__ void k_split(const int* __restrict__ i_s, const int* __restrict__ j_s,
                        const int* __restrict__ gscan, const int* __restrict__ bscan,
                        int* __restrict__ pairs, int nbAh, int nbins, int E,
                        int shift, int jbits) {
    __shared__ int cur[512];
    int t = threadIdx.x, blk = blockIdx.x;
    for (int b = t; b < nbins; b += 512)
        cur[b] = scanned(gscan, bscan, b * nbAh + 2 * blk);
    __syncthreads();
    int fmask = (1 << shift) - 1;
    int base = blk * CHUNKS;
    int end = min(base + CHUNKS, E);
    for (int k = base + t; k < end; k += 512) {
        int i = i_s[k];
        int pos = atomicAdd(&cur[i >> shift], 1);          // LDS atomic
        pairs[pos] = ((i & fmask) << jbits) | j_s[k];
    }
}

// ---------------- pass 1: density — NSUB sub-blocks per coarse bin ---------
__global__ void k_rho_bin(const float4* __restrict__ pos4, const int* __restrict__ pairs,
                          const int* __restrict__ gscan, const int* __restrict__ bscan,
                          float* __restrict__ part_rho, int nbAh, int n, int E,
                          int shift, int jbits, int nbins) {
    __shared__ float srho[256];
    __shared__ float4 spos[256];
    __shared__ int sse[2];
    int bin = blockIdx.x >> 3, sub = blockIdx.x & (NSUB - 1);
    int t = threadIdx.x;
    int lo = bin << shift;
    srho[t] = 0.f;
    int ii = lo + t;
    spos[t] = (ii < n) ? pos4[ii] : make_float4(0.f, 0.f, 0.f, 0.f);
    if (t == 0) {
        sse[0] = scanned(gscan, bscan, bin * nbAh);
        sse[1] = (bin + 1 < nbins) ? scanned(gscan, bscan, (bin + 1) * nbAh) : E;
    }
    __syncthreads();
    int s = sse[0], len = sse[1] - sse[0];
    int k0 = s + (int)((long)len * sub / NSUB);
    int k1 = s + (int)((long)len * (sub + 1) / NSUB);
    int jm = (1 << jbits) - 1;
    for (int k = k0 + t; k < k1; k += 256) {
        int pr = pairs[k];                   // coalesced
        int slot = pr >> jbits, j = pr & jm;
        float4 rj = pos4[j];                 // divergent gather (1.6MB, L2-hot)
        float4 ri = spos[slot];
        float dx = ri.x - rj.x, dy = ri.y - rj.y, dz = ri.z - rj.z;
        float d = sqrtf(dx * dx + dy * dy + dz * dz);
        float t1 = fmaxf(1.f - d, 0.f);
        float t2 = fmaxf(2.f - d, 0.f);
        float t3 = fmaxf(3.f - d, 0.f);
        float w = kSigma * (pow5f(t3) - 6.f * pow5f(t2) + 15.f * pow5f(t1));
        atomicAdd(&srho[slot], w);           // LDS float atomic
    }
    __syncthreads();
    if (ii < n) part_rho[(size_t)sub * n + ii] = srho[t];   // coalesced
}

// ---------------- reduce rho partials; fused per-particle state -------------
__global__ void k_reduce_rho(const float* __restrict__ part_rho,
                             const float4* __restrict__ pos4, const float* __restrict__ v,
                             float4* __restrict__ pv8, float* __restrict__ out, int n) {
    int i = blockIdx.x * blockDim.x + threadIdx.x;
    if (i >= n) return;
    float rh = 0.f;
    for (int s = 0; s < NSUB; s++) rh += part_rho[(size_t)s * n + i];
    float pp = kPRef * (rh - 1.0f);
    float4 sp = pos4[i];
    pv8[2 * i]     = make_float4(sp.x, sp.y, sp.z, rh);
    pv8[2 * i + 1] = make_float4(v[3 * i], v[3 * i + 1], v[3 * i + 2], pp);
    float* o = out + (size_t)i * 8;
    o[0] = rh;
    o[1] = pp;
    o[5] = 0.f; o[6] = 0.f; o[7] = 0.f;      // dvdt == 0 exactly
}

// ---------------- pass 2: acceleration — NSUB sub-blocks per bin -----------
__global__ void k_acc_bin(const float4* __restrict__ pv8, const int* __restrict__ pairs,
                          const int* __restrict__ gscan, const int* __restrict__ bscan,
                          float* __restrict__ part_ax, float* __restrict__ part_ay,
                          float* __restrict__ part_az, int nbAh, int n, int E,
                          int shift, int jbits, int nbins) {
    __shared__ float sax[256], say[256], saz[256];
    __shared__ float4 sab[512];              // {r,rho | v,p} interleaved per slot
    __shared__ int sse[2];
    int bin = blockIdx.x >> 3, sub = blockIdx.x & (NSUB - 1);
    int t = threadIdx.x;
    int lo = bin << shift;
    sax[t] = 0.f; say[t] = 0.f; saz[t] = 0.f;
    for (int q = t; q < 512; q += 256) {
        int gi = 2 * lo + q;
        sab[q] = (gi < 2 * n) ? pv8[gi] : make_float4(1.f, 1.f, 1.f, 1.f);
    }
    if (t == 0) {
        sse[0] = scanned(gscan, bscan, bin * nbAh);
        sse[1] = (bin + 1 < nbins) ? scanned(gscan, bscan, (bin + 1) * nbAh) : E;
    }
    __syncthreads();
    int s = sse[0], len = sse[1] - sse[0];
    int k0 = s + (int)((long)len * sub / NSUB);
    int k1 = s + (int)((long)len * (sub + 1) / NSUB);
    int jm = (1 << jbits) - 1;
    for (int k = k0 + t; k < k1; k += 256) {
        int pr = pairs[k];                   // coalesced
        int slot = pr >> jbits, j = pr & jm;
        float4 aj = pv8[2 * j];              // divergent gather, 64B line
        float4 bj = pv8[2 * j + 1];          // same line (L1 hit)
        float4 ai = sab[2 * slot];
        float4 bi = sab[2 * slot + 1];
        float rho_i = ai.w, p_i = bi.w;
        float rho_j = aj.w, p_j = bj.w;
        float dx = ai.x - aj.x, dy = ai.y - aj.y, dz = ai.z - aj.z;
        float d = sqrtf(dx * dx + dy * dy + dz * dz);
        float t1 = fmaxf(1.f - d, 0.f);
        float t2 = fmaxf(2.f - d, 0.f);
        float t3 = fmaxf(3.f - d, 0.f);
        float gw = kSigma * (-5.f * pow4f(t3) + 30.f * pow4f(t2) - 75.f * pow4f(t1));
        float inv_i = 1.0f / rho_i, inv_j = 1.0f / rho_j;
        float c = (inv_i * inv_i + inv_j * inv_j) * gw / (d + kEps);
        float p_ij = (rho_j * p_i + rho_i * p_j) / (rho_i + rho_j);
        atomicAdd(&sax[slot], c * (kEta * (bi.x - bj.x) - p_ij * dx));
        atomicAdd(&say[slot], c * (kEta * (bi.y - bj.y) - p_ij * dy));
        atomicAdd(&saz[slot], c * (kEta * (bi.z - bj.z) - p_ij * dz));
    }
    __syncthreads();
    int ii = lo + t;
    if (ii < n) {
        size_t o = (size_t)sub * n + ii;     // coalesced
        part_ax[o] = sax[t];
        part_ay[o] = say[t];
        part_az[o] = saz[t];
    }
}

// ---------------- reduce acc partials ----------------
__global__ void k_reduce_acc(const float* __restrict__ part_ax,
                             const float* __restrict__ part_ay,
                             const float* __restrict__ part_az,
                             float* __restrict__ out, int n) {
    int i = blockIdx.x * blockDim.x + threadIdx.x;
    if (i >= n) return;
    float ax = 0.f, ay = 0.f, az = 0.f;
    for (int s = 0; s < NSUB; s++) {
        size_t o = (size_t)s * n + i;
        ax += part_ax[o]; ay += part_ay[o]; az += part_az[o];
    }
    float* o = out + (size_t)i * 8 + 2;
    o[0] = ax; o[1] = ay; o[2] = az;
}

// ---------------- launch ----------------
static inline char* wcarve(char*& ws, size_t bytes) {
    char* p = ws;
    ws += (bytes + 255) & ~(size_t)255;
    return p;
}

extern "C" void kernel_launch(void* const* d_in, const int* in_sizes, int n_in,
                              void* d_out, int out_size, void* d_ws, size_t ws_size,
                              hipStream_t stream) {
    const float* r = (const float*)d_in[0];
    const float* v = (const float*)d_in[1];
    const int* i_s = (const int*)d_in[2];
    const int* j_s = (const int*)d_in[3];
    int n = in_sizes[0] / 3;
    int E = in_sizes[2];
    float* out = (float*)d_out;

    int shift = 8;                                 // 256 particles per coarse bin
    int nbins = ((n - 1) >> shift) + 1;
    while (nbins > 512) { shift++; nbins = ((n - 1) >> shift) + 1; }  // safety
    int jbits = 1;
    while ((1 << jbits) < n) jbits++;              // 17 for n = 100k

    int nbAh = (E + CHUNKH - 1) / CHUNKH;          // 782 hist blocks
    int nbAs = (E + CHUNKS - 1) / CHUNKS;          // 391 split blocks
    int m = nbins * nbAh;                          // scan length (~306k)
    int nb2 = (m + 255) / 256;

    char* ws = (char*)d_ws;
    float4* pos4    = (float4*)wcarve(ws, (size_t)n * 16);
    float4* pv8     = (float4*)wcarve(ws, (size_t)n * 32);
    int*    ghist   = (int*)wcarve(ws, (size_t)m * 4);
    int*    gscan   = (int*)wcarve(ws, (size_t)m * 4);
    int*    bsum    = (int*)wcarve(ws, (size_t)nb2 * 4);
    int*    bscan   = (int*)wcarve(ws, (size_t)nb2 * 4);
    int*    pairs   = (int*)wcarve(ws, (size_t)E * 4);
    float*  part_rho= (float*)wcarve(ws, (size_t)NSUB * n * 4);
    float*  part_ax = (float*)wcarve(ws, (size_t)NSUB * n * 4);
    float*  part_ay = (float*)wcarve(ws, (size_t)NSUB * n * 4);
    float*  part_az = (float*)wcarve(ws, (size_t)NSUB * n * 4);

    const int bs = 256;
    int gn = (n + bs - 1) / bs;

    k_pack<<<gn, bs, 0, stream>>>(r, pos4, n);
    k_hist<<<nbAh, 256, 0, stream>>>(i_s, ghist, nbAh, nbins, E, shift);
    k_scan_block<<<nb2, 256, 0, stream>>>(ghist, gscan, bsum, m);
    k_scan_bsums<<<1, 512, 0, stream>>>(bsum, bscan, nb2);
    k_split<<<nbAs, 512, 0, stream>>>(i_s, j_s, gscan, bscan, pairs, nbAh, nbins, E, shift, jbits);
    k_rho_bin<<<nbins * NSUB, 256, 0, stream>>>(pos4, pairs, gscan, bscan, part_rho, nbAh, n, E, shift, jbits, nbins);
    k_reduce_rho<<<gn, bs, 0, stream>>>(part_rho, pos4, v, pv8, out, n);
    k_acc_bin<<<nbins * NSUB, 256, 0, stream>>>(pv8, pairs, gscan, bscan, part_ax, part_ay, part_az, nbAh, n, E, shift, jbits, nbins);
    k_reduce_acc<<<gn, bs, 0, stream>>>(part_ax, part_ay, part_az, out, n);
}